// Round 1
// baseline (37401.379 us; speedup 1.0000x reference)
//
#include <hip/hip_runtime.h>
#include <math.h>

#define B 128
#define H 256
#define V 130
#define L 100
#define G3 768  // 3*H

__device__ __forceinline__ float sigmoidf_(float x) { return 1.0f / (1.0f + expf(-x)); }

// ---------------------------------------------------------------------------
// Generic GRU gate kernel.
// tile: 32 rows x 8 output h-cols per block (256 threads, 1 output/thread).
// grid: dim3(32, nrows/32) -> (col-blocks, row-blocks); nrows = 128.
// NCHUNK input chunks, each a [B][H] activation array; the LAST chunk is the
// h_old chunk (multiplied by whh); earlier chunks use wih cols [c*256, c*256+256).
// zadd: precomputed (z-part @ wih_z.T + bih) per row, [B][768]; or null -> bih[768].
// ---------------------------------------------------------------------------
template <int NCHUNK>
__global__ __launch_bounds__(256) void gru_gates(
    const float* __restrict__ x0, const float* __restrict__ x1,
    const float* __restrict__ x2, const float* __restrict__ x3,
    const float* __restrict__ wih, int wih_k,
    const float* __restrict__ whh,
    const float* __restrict__ zadd, const float* __restrict__ bih,
    const float* __restrict__ bhh,
    float* __restrict__ out0, float* __restrict__ out1)
{
  __shared__ float xs[32][260];  // padded: row stride 1040B (16B aligned)
  const int tid = threadIdx.x;
  const int r   = tid & 31;      // row within tile
  const int hc  = tid >> 5;      // 0..7 col within tile (wave = 2 cols -> weight broadcast)
  const int row0 = blockIdx.y * 32;
  const int col  = blockIdx.x * 8 + hc;   // 0..255 output h-col

  float giR = 0.f, giZ = 0.f, giN = 0.f;
  float ghR = 0.f, ghZ = 0.f, ghN = 0.f;
  float hold = 0.f;

  for (int c = 0; c < NCHUNK; ++c) {
    const float* src = (c == 0) ? x0 : (c == 1) ? x1 : (c == 2) ? x2 : x3;
    // stage 32 rows x 256 cols of this chunk into LDS (coalesced float4)
    for (int j = tid; j < 32 * 64; j += 256) {
      const int rr = j >> 6, k4 = (j & 63) << 2;
      const float4 v = *reinterpret_cast<const float4*>(src + (size_t)(row0 + rr) * H + k4);
      *reinterpret_cast<float4*>(&xs[rr][k4]) = v;
    }
    __syncthreads();

    const bool is_h = (c == NCHUNK - 1);
    const float* wR;
    const float* wZ;
    const float* wN;
    if (is_h) {
      wR = whh + (size_t)(col) * 256;
      wZ = whh + (size_t)(256 + col) * 256;
      wN = whh + (size_t)(512 + col) * 256;
    } else {
      const float* wb = wih + c * 256;  // column offset inside the wih row
      wR = wb + (size_t)(col) * wih_k;
      wZ = wb + (size_t)(256 + col) * wih_k;
      wN = wb + (size_t)(512 + col) * wih_k;
    }

    float aR = 0.f, aZ = 0.f, aN = 0.f;
#pragma unroll 8
    for (int k = 0; k < 256; k += 4) {
      const float4 xv = *reinterpret_cast<const float4*>(&xs[r][k]);
      const float4 vR = *reinterpret_cast<const float4*>(wR + k);
      const float4 vZ = *reinterpret_cast<const float4*>(wZ + k);
      const float4 vN = *reinterpret_cast<const float4*>(wN + k);
      aR += xv.x * vR.x; aR += xv.y * vR.y; aR += xv.z * vR.z; aR += xv.w * vR.w;
      aZ += xv.x * vZ.x; aZ += xv.y * vZ.y; aZ += xv.z * vZ.z; aZ += xv.w * vZ.w;
      aN += xv.x * vN.x; aN += xv.y * vN.y; aN += xv.z * vN.z; aN += xv.w * vN.w;
    }
    if (is_h) {
      ghR = aR; ghZ = aZ; ghN = aN;
      hold = xs[r][col];  // h_old still resident in LDS (last chunk)
    } else {
      giR += aR; giZ += aZ; giN += aN;
    }
    if (c != NCHUNK - 1) __syncthreads();
  }

  float bR, bZ, bN;
  if (zadd) {
    const float* zp = zadd + (size_t)(row0 + r) * G3;
    bR = zp[col]; bZ = zp[256 + col]; bN = zp[512 + col];
  } else {
    bR = bih[col]; bZ = bih[256 + col]; bN = bih[512 + col];
  }
  const float hR = ghR + bhh[col];
  const float hZ = ghZ + bhh[256 + col];
  const float hN = ghN + bhh[512 + col];

  const float rg = sigmoidf_(giR + bR + hR);
  const float ug = sigmoidf_(giZ + bZ + hZ);
  const float ng = tanhf(giN + bN + rg * hN);
  const float hnew = (1.f - ug) * ng + ug * hold;

  const size_t oidx = (size_t)(row0 + r) * H + col;
  out0[oidx] = hnew;
  if (out1) out1[oidx] = hnew;
}

// ---------------------------------------------------------------------------
// logits = (u + h2) @ ow.T + ob ; write to d_out ; argmax (first-index ties);
// note_i[row] = embi[argmax]
// 16 blocks x 256 threads; 8 rows/block, 32 lanes/row.
// ---------------------------------------------------------------------------
__global__ __launch_bounds__(256) void out_argmax(
    const float* __restrict__ u, const float* __restrict__ h2,
    const float* __restrict__ ow, const float* __restrict__ ob,
    const float* __restrict__ embi,
    float* __restrict__ note_i, float* __restrict__ outp)
{
  __shared__ float s[8][260];
  const int tid = threadIdx.x;
  const int r = tid >> 5;      // 0..7
  const int l = tid & 31;      // lane in 32-group
  const int row0 = blockIdx.x * 8;

  for (int j = tid; j < 8 * 64; j += 256) {
    const int rr = j >> 6, k4 = (j & 63) << 2;
    const float4 a = *reinterpret_cast<const float4*>(u  + (size_t)(row0 + rr) * H + k4);
    const float4 b = *reinterpret_cast<const float4*>(h2 + (size_t)(row0 + rr) * H + k4);
    float4 vv; vv.x = a.x + b.x; vv.y = a.y + b.y; vv.z = a.z + b.z; vv.w = a.w + b.w;
    *reinterpret_cast<float4*>(&s[rr][k4]) = vv;
  }
  __syncthreads();

  float best = -INFINITY;
  int bidx = 0;
  for (int m = 0; m < 5; ++m) {
    const int v = l + (m << 5);
    if (v < V) {
      float acc = 0.f;
      const float* wrow = ow + (size_t)v * H;
#pragma unroll 8
      for (int k = 0; k < 256; k += 4) {
        const float4 xv = *reinterpret_cast<const float4*>(&s[r][k]);
        const float4 wv = *reinterpret_cast<const float4*>(wrow + k);
        acc += xv.x * wv.x; acc += xv.y * wv.y; acc += xv.z * wv.z; acc += xv.w * wv.w;
      }
      acc += ob[v];
      outp[(size_t)(row0 + r) * (L * V) + v] = acc;
      if (acc > best) { best = acc; bidx = v; }  // v ascends per-lane -> first-max kept
    }
  }
  for (int off = 16; off > 0; off >>= 1) {
    const float ov = __shfl_xor(best, off, 32);
    const int   oi = __shfl_xor(bidx, off, 32);
    if (ov > best || (ov == best && oi < bidx)) { best = ov; bidx = oi; }
  }
  const float* erow = embi + (size_t)bidx * H;
  float* nrow = note_i + (size_t)(row0 + r) * H;
  const int k0 = l * 8;
  *reinterpret_cast<float4*>(nrow + k0)     = *reinterpret_cast<const float4*>(erow + k0);
  *reinterpret_cast<float4*>(nrow + k0 + 4) = *reinterpret_cast<const float4*>(erow + k0 + 4);
}

// hidden = tanh(z @ hid_w.T + hid_b)
__global__ __launch_bounds__(256) void hid_kernel(
    const float* __restrict__ z, const float* __restrict__ hw,
    const float* __restrict__ hb, float* __restrict__ hidden)
{
  __shared__ float xs[32][260];
  const int tid = threadIdx.x;
  const int r = tid & 31, hc = tid >> 5;
  const int row0 = blockIdx.y * 32;
  const int col = blockIdx.x * 8 + hc;
  for (int j = tid; j < 32 * 64; j += 256) {
    const int rr = j >> 6, k4 = (j & 63) << 2;
    *reinterpret_cast<float4*>(&xs[rr][k4]) =
        *reinterpret_cast<const float4*>(z + (size_t)(row0 + rr) * H + k4);
  }
  __syncthreads();
  float acc = 0.f;
  const float* wrow = hw + (size_t)col * H;
#pragma unroll 8
  for (int k = 0; k < 256; k += 4) {
    const float4 xv = *reinterpret_cast<const float4*>(&xs[r][k]);
    const float4 wv = *reinterpret_cast<const float4*>(wrow + k);
    acc += xv.x * wv.x; acc += xv.y * wv.y; acc += xv.z * wv.z; acc += xv.w * wv.w;
  }
  hidden[(size_t)(row0 + r) * H + col] = tanhf(acc + hb[col]);
}

// zout[(s*B+row)*768 + g] = sum_k z[row][k] * wih[s*768+g][256+k] + bih[s*768+g]
__global__ __launch_bounds__(256) void zpre_kernel(
    const float* __restrict__ z, const float* __restrict__ wih,
    const float* __restrict__ bih, float* __restrict__ zout)
{
  __shared__ float xs[32][260];
  const int tid = threadIdx.x;
  const int r = tid & 31, hc = tid >> 5;
  const int row0 = blockIdx.y * 32;
  const int gr = blockIdx.x * 8 + hc;   // 0..2303
  const int s = gr / 768;
  const int g = gr - s * 768;
  for (int j = tid; j < 32 * 64; j += 256) {
    const int rr = j >> 6, k4 = (j & 63) << 2;
    *reinterpret_cast<float4*>(&xs[rr][k4]) =
        *reinterpret_cast<const float4*>(z + (size_t)(row0 + rr) * H + k4);
  }
  __syncthreads();
  float acc = 0.f;
  const float* wrow = wih + (size_t)gr * 512 + 256;
#pragma unroll 8
  for (int k = 0; k < 256; k += 4) {
    const float4 xv = *reinterpret_cast<const float4*>(&xs[r][k]);
    const float4 wv = *reinterpret_cast<const float4*>(wrow + k);
    acc += xv.x * wv.x; acc += xv.y * wv.y; acc += xv.z * wv.z; acc += xv.w * wv.w;
  }
  zout[((size_t)(s * B + row0 + r)) * G3 + g] = acc + bih[gr];
}

__global__ __launch_bounds__(256) void init_copy(
    const float* __restrict__ hidden, float* __restrict__ g1h0,
    float* __restrict__ h20, float* __restrict__ ctx0)
{
  const int e = blockIdx.x * 256 + threadIdx.x;  // 0..B*H
  const float v = hidden[e];
  ctx0[e] = v;
  for (int s = 0; s < 3; ++s) {
    g1h0[(size_t)s * B * H + e] = v;
    h20[(size_t)s * B * H + e] = v;
  }
}

__global__ __launch_bounds__(256) void init_note(
    const float* __restrict__ emb, float* __restrict__ note)
{
  const int e = blockIdx.x * 256 + threadIdx.x;  // 0..3*B*H
  const int s = e / (B * H);
  const int c = e & (H - 1);
  note[e] = emb[(size_t)s * V * H + c];  // emb[s][0][c]
}

extern "C" void kernel_launch(void* const* d_in, const int* in_sizes, int n_in,
                              void* d_out, int out_size, void* d_ws, size_t ws_size,
                              hipStream_t stream) {
  const float* z     = (const float*)d_in[0];
  const float* g1wih = (const float*)d_in[1];
  const float* g1whh = (const float*)d_in[2];
  const float* g1bih = (const float*)d_in[3];
  const float* g1bhh = (const float*)d_in[4];
  const float* g2wih = (const float*)d_in[5];
  const float* g2whh = (const float*)d_in[6];
  const float* g2bih = (const float*)d_in[7];
  const float* g2bhh = (const float*)d_in[8];
  const float* cwih  = (const float*)d_in[9];
  const float* cwhh  = (const float*)d_in[10];
  const float* cbih  = (const float*)d_in[11];
  const float* cbhh  = (const float*)d_in[12];
  const float* outw  = (const float*)d_in[13];
  const float* outb  = (const float*)d_in[14];
  const float* hidw  = (const float*)d_in[15];
  const float* hidb  = (const float*)d_in[16];
  const float* emb   = (const float*)d_in[17];
  float* out = (float*)d_out;

  float* ws = (float*)d_ws;
  size_t off = 0;
  auto alloc = [&](size_t n) { float* p = ws + off; off += n; return p; };
  float* hidden = alloc((size_t)B * H);
  float* Z1     = alloc((size_t)3 * B * G3);
  float* Z2     = alloc((size_t)3 * B * G3);
  float* g1h[2] = {alloc((size_t)3 * B * H), alloc((size_t)3 * B * H)};
  float* h2b[2] = {alloc((size_t)3 * B * H), alloc((size_t)3 * B * H)};
  float* ctx[2] = {alloc((size_t)B * H), alloc((size_t)B * H)};
  float* U0     = alloc((size_t)3 * B * H);
  float* U1     = alloc((size_t)3 * B * H);
  float* note   = alloc((size_t)3 * B * H);

  const dim3 blk(256);
  const dim3 grd32(32, 4);

  hid_kernel<<<grd32, blk, 0, stream>>>(z, hidw, hidb, hidden);
  zpre_kernel<<<dim3(288, 4), blk, 0, stream>>>(z, g1wih, g1bih, Z1);
  zpre_kernel<<<dim3(288, 4), blk, 0, stream>>>(z, g2wih, g2bih, Z2);
  init_copy<<<128, blk, 0, stream>>>(hidden, g1h[0], h2b[0], ctx[0]);
  init_note<<<384, blk, 0, stream>>>(emb, note);

  for (int t = 0; t < L; ++t) {
    const int rb = t & 1, wb = (t + 1) & 1;
    // Phase A: gru1 per stream; writes new g1h bank and U0 (= unroll)
    for (int s = 0; s < 3; ++s) {
      gru_gates<2><<<grd32, blk, 0, stream>>>(
          note + (size_t)s * B * H, g1h[rb] + (size_t)s * B * H, nullptr, nullptr,
          g1wih + (size_t)s * G3 * 512, 512, g1whh + (size_t)s * G3 * H,
          Z1 + (size_t)s * B * G3, nullptr, g1bhh + (size_t)s * G3,
          g1h[wb] + (size_t)s * B * H, U0 + (size_t)s * B * H);
    }
    for (int i = 0; i < 3; ++i) {
      const int j = 3 * t + i;
      const float* us[3];
      for (int s2 = 0; s2 < 3; ++s2)
        us[s2] = (s2 < i ? U1 : U0) + (size_t)s2 * B * H;
      // ctx GRU: chunks u0,u1,u2 (wih cols 0/256/512) + ctx_old (whh)
      gru_gates<4><<<grd32, blk, 0, stream>>>(
          us[0], us[1], us[2], ctx[j & 1],
          cwih, 768, cwhh,
          nullptr, cbih, cbhh,
          ctx[(j + 1) & 1], nullptr);
      // gru2[i]: chunks ctx_new + h2_old
      gru_gates<2><<<grd32, blk, 0, stream>>>(
          ctx[(j + 1) & 1], h2b[rb] + (size_t)i * B * H, nullptr, nullptr,
          g2wih + (size_t)i * G3 * 512, 512, g2whh + (size_t)i * G3 * H,
          Z2 + (size_t)i * B * G3, nullptr, g2bhh + (size_t)i * G3,
          h2b[wb] + (size_t)i * B * H, nullptr);
      // logits + argmax + note update
      out_argmax<<<16, blk, 0, stream>>>(
          U0 + (size_t)i * B * H, h2b[wb] + (size_t)i * B * H,
          outw + (size_t)i * V * H, outb + (size_t)i * V, emb + (size_t)i * V * H,
          note + (size_t)i * B * H, out + (size_t)i * B * L * V + (size_t)t * V);
      // unroll-gru (fixed gru1[1] weights, faithful to reference)
      gru_gates<2><<<grd32, blk, 0, stream>>>(
          note + (size_t)i * B * H, U0 + (size_t)i * B * H, nullptr, nullptr,
          g1wih + (size_t)1 * G3 * 512, 512, g1whh + (size_t)1 * G3 * H,
          Z1 + (size_t)1 * B * G3, nullptr, g1bhh + (size_t)1 * G3,
          U1 + (size_t)i * B * H, nullptr);
    }
  }
}